// Round 2
// 616.853 us; speedup vs baseline: 1.1784x; 1.1784x over previous
//
#include <hip/hip_runtime.h>
#include <hip/hip_fp16.h>

#define NN 100000      // nodes
#define NE 1600000     // edges
#define F0 512         // NFEAT
#define F1 128         // NHID
#define F2 64          // NCLASS

typedef short bf16x8 __attribute__((ext_vector_type(8)));
typedef float f32x4  __attribute__((ext_vector_type(4)));

// fp32 -> bf16 (round-to-nearest-even, finite inputs)
static __device__ __forceinline__ unsigned short f2bf(float f) {
    unsigned int u = __float_as_uint(f);
    return (unsigned short)((u + 0x7FFFu + ((u >> 16) & 1u)) >> 16);
}

// fp32 -> fp16 bits (RNE)
static __device__ __forceinline__ unsigned short f2h(float f) {
    __half h = __float2half(f);
    return *(unsigned short*)&h;
}

// packed 2xfp16 -> 2xfp32
static __device__ __forceinline__ float2 h2f2(unsigned int u) {
    __half2 h = *(__half2*)&u;
    return __half22float2(h);
}

// ---------------------------------------------------------------------------
// Pre-transpose + convert weights: W1[512,128] -> W1t[128,512] bf16,
//                                  W2[128,64]  -> W2t[64,128]  bf16.
// ---------------------------------------------------------------------------
__global__ __launch_bounds__(256)
void wt_kernel(const float* __restrict__ W1, const float* __restrict__ W2,
               unsigned short* __restrict__ W1t, unsigned short* __restrict__ W2t)
{
    int i = blockIdx.x * 256 + threadIdx.x;
    if (i < F0 * F1) {
        int n = i / F0, k = i % F0;
        W1t[i] = f2bf(W1[k * F1 + n]);
    } else {
        int j = i - F0 * F1;
        if (j < F1 * F2) {
            int n = j / F1, k = j % F1;
            W2t[j] = f2bf(W2[k * F2 + n]);
        }
    }
}

// ---------------------------------------------------------------------------
// bf16 MFMA GEMM: C[M,N] = A[M,K] @ B[K,N], A fp32 (converted on the fly),
// B pre-transposed bf16 Bt[N,K]. N == BN (single col block).
// C: fp16 output (halves the downstream gather bytes).
// 256 threads = 4 waves; wave w computes rows [w*32, w*32+32) x all BN cols
// as 2 x TN tiles of 16x16, K-stepped by 32 (mfma_f32_16x16x32_bf16).
// ---------------------------------------------------------------------------
template<int BM, int BN, int BK, int TN>
__global__ __launch_bounds__(256)
void mfma_gemm(const float* __restrict__ A, const unsigned short* __restrict__ Bt,
               unsigned short* __restrict__ C, int M, int K, int N)
{
    constexpr int LDA = BK + 8;   // pad: 72 shorts = 144 B = 36 banks
    constexpr int LDB = BK + 8;
    __shared__ unsigned short As[BM * LDA];
    __shared__ unsigned short Bs[BN * LDB];

    const int tid  = threadIdx.x;
    const int wave = tid >> 6;
    const int lane = tid & 63;
    const int lr   = lane & 15;
    const int quad = lane >> 4;
    const int row0 = blockIdx.x * BM;

    f32x4 acc[2][TN];
#pragma unroll
    for (int i = 0; i < 2; i++)
#pragma unroll
        for (int j = 0; j < TN; j++) acc[i][j] = (f32x4)0.f;

    for (int k0 = 0; k0 < K; k0 += BK) {
        // --- stage A tile (BM x BK) fp32 -> bf16 ---
#pragma unroll
        for (int l = tid; l < BM * (BK / 4); l += 256) {
            int m  = l / (BK / 4);
            int kq = l % (BK / 4);
            int rg = row0 + m; if (rg >= M) rg = M - 1;
            float4 v = *(const float4*)(A + (long long)rg * K + k0 + kq * 4);
            ushort4 b = make_ushort4(f2bf(v.x), f2bf(v.y), f2bf(v.z), f2bf(v.w));
            *(ushort4*)(&As[m * LDA + kq * 4]) = b;
        }
        // --- stage B tile (BN x BK) from Bt[N,K] (already bf16) ---
#pragma unroll
        for (int l = tid; l < BN * (BK / 8); l += 256) {
            int n  = l / (BK / 8);
            int ko = l % (BK / 8);
            uint4 v = *(const uint4*)(Bt + (long long)n * K + k0 + ko * 8);
            *(uint4*)(&Bs[n * LDB + ko * 8]) = v;
        }
        __syncthreads();

#pragma unroll
        for (int kk = 0; kk < BK; kk += 32) {
            bf16x8 a[2], b[TN];
#pragma unroll
            for (int tm = 0; tm < 2; tm++)
                a[tm] = *(const bf16x8*)(&As[(wave * 32 + tm * 16 + lr) * LDA + kk + quad * 8]);
#pragma unroll
            for (int tn = 0; tn < TN; tn++)
                b[tn] = *(const bf16x8*)(&Bs[(tn * 16 + lr) * LDB + kk + quad * 8]);
#pragma unroll
            for (int tm = 0; tm < 2; tm++)
#pragma unroll
                for (int tn = 0; tn < TN; tn++)
                    acc[tm][tn] = __builtin_amdgcn_mfma_f32_16x16x32_bf16(
                        a[tm], b[tn], acc[tm][tn], 0, 0, 0);
        }
        __syncthreads();
    }

    // --- epilogue: C/D layout col=lane&15, row=quad*4+reg; store fp16 ---
#pragma unroll
    for (int tm = 0; tm < 2; tm++) {
#pragma unroll
        for (int r = 0; r < 4; r++) {
            int row = row0 + wave * 32 + tm * 16 + quad * 4 + r;
            if (row < M) {
#pragma unroll
                for (int tn = 0; tn < TN; tn++)
                    C[(long long)row * N + tn * 16 + lr] = f2h(acc[tm][tn][r]);
            }
        }
    }
}

// ---------------------------------------------------------------------------
// CSR build: histogram+rank, 3-phase exclusive scan, fill (no 2nd atomic pass)
// ---------------------------------------------------------------------------
__global__ __launch_bounds__(256)
void hist_kernel(const int* __restrict__ dst, int* __restrict__ cnt,
                 int* __restrict__ rank, int ne)
{
    int e = blockIdx.x * 256 + threadIdx.x;
    if (e < ne) rank[e] = atomicAdd(&cnt[dst[e]], 1);
}

__global__ __launch_bounds__(256)
void scan1_kernel(const int* __restrict__ cnt, int* __restrict__ rowptr,
                  int* __restrict__ bsum, int n)
{
    __shared__ int s[256];
    int t = threadIdx.x;
    int i = blockIdx.x * 256 + t;
    int v = (i < n) ? cnt[i] : 0;
    s[t] = v;
    __syncthreads();
#pragma unroll
    for (int off = 1; off < 256; off <<= 1) {
        int x = (t >= off) ? s[t - off] : 0;
        __syncthreads();
        s[t] += x;
        __syncthreads();
    }
    if (i < n) rowptr[i] = s[t] - v;
    if (t == 255) bsum[blockIdx.x] = s[255];
}

__global__ __launch_bounds__(512)
void scan2_kernel(int* __restrict__ bsum, int nb, int* __restrict__ rowptr, int n, int ne)
{
    __shared__ int s[512];
    int t = threadIdx.x;
    int v = (t < nb) ? bsum[t] : 0;
    s[t] = v;
    __syncthreads();
#pragma unroll
    for (int off = 1; off < 512; off <<= 1) {
        int x = (t >= off) ? s[t - off] : 0;
        __syncthreads();
        s[t] += x;
        __syncthreads();
    }
    if (t < nb) bsum[t] = s[t] - v;
    if (t == 0) rowptr[n] = ne;
}

__global__ __launch_bounds__(256)
void scan3_kernel(int* __restrict__ rowptr, const int* __restrict__ bsum, int n)
{
    int i = blockIdx.x * 256 + threadIdx.x;
    if (i < n) rowptr[i] += bsum[i >> 8];
}

__global__ __launch_bounds__(256)
void fill_kernel(const int* __restrict__ src, const int* __restrict__ dst,
                 const float* __restrict__ ew, const int* __restrict__ rowptr,
                 const int* __restrict__ rank, int2* __restrict__ rec, int ne)
{
    int e = blockIdx.x * 256 + threadIdx.x;
    if (e >= ne) return;
    int d = dst[e];
    int pos = rowptr[d] + rank[e];
    rec[pos] = make_int2(src[e], __float_as_int(ew[e]));
}

// ---------------------------------------------------------------------------
// Fused aggregation layer 1: one wave per node, 2 feats/lane (F1=128).
// sup is fp16-packed (2 feats per uint). Writes fp32 h (output embedding).
// ---------------------------------------------------------------------------
__global__ __launch_bounds__(256)
void agg1_kernel(const unsigned int* __restrict__ sup, const int2* __restrict__ rec,
                 const int* __restrict__ rowptr, const float2* __restrict__ b1,
                 float2* __restrict__ h, int n)
{
    int node = blockIdx.x * 4 + (threadIdx.x >> 6);
    int lane = threadIdx.x & 63;
    if (node >= n) return;

    int j   = rowptr[node];
    int end = rowptr[node + 1];
    float2 acc = make_float2(0.f, 0.f);

    for (; j + 4 <= end; j += 4) {
        int2 r0 = rec[j];
        int2 r1 = rec[j + 1];
        int2 r2 = rec[j + 2];
        int2 r3 = rec[j + 3];
        unsigned int u0 = sup[(long long)r0.x * 64 + lane];
        unsigned int u1 = sup[(long long)r1.x * 64 + lane];
        unsigned int u2 = sup[(long long)r2.x * 64 + lane];
        unsigned int u3 = sup[(long long)r3.x * 64 + lane];
        float w0 = __int_as_float(r0.y);
        float w1 = __int_as_float(r1.y);
        float w2 = __int_as_float(r2.y);
        float w3 = __int_as_float(r3.y);
        float2 f0 = h2f2(u0);
        float2 f1 = h2f2(u1);
        float2 f2 = h2f2(u2);
        float2 f3 = h2f2(u3);
        acc.x = fmaf(f0.x, w0, acc.x);  acc.y = fmaf(f0.y, w0, acc.y);
        acc.x = fmaf(f1.x, w1, acc.x);  acc.y = fmaf(f1.y, w1, acc.y);
        acc.x = fmaf(f2.x, w2, acc.x);  acc.y = fmaf(f2.y, w2, acc.y);
        acc.x = fmaf(f3.x, w3, acc.x);  acc.y = fmaf(f3.y, w3, acc.y);
    }
    for (; j < end; j++) {
        int2 r0 = rec[j];
        unsigned int u0 = sup[(long long)r0.x * 64 + lane];
        float w0 = __int_as_float(r0.y);
        float2 f0 = h2f2(u0);
        acc.x = fmaf(f0.x, w0, acc.x);
        acc.y = fmaf(f0.y, w0, acc.y);
    }

    float2 bb = b1[lane];
    acc.x += bb.x;
    acc.y += bb.y;
    acc.x = acc.x > 0.f ? acc.x : 0.01f * acc.x;
    acc.y = acc.y > 0.f ? acc.y : 0.01f * acc.y;
    h[(long long)node * 64 + lane] = acc;
}

// ---------------------------------------------------------------------------
// Fused aggregation layer 2 + softmax: one wave per node (F2=64), fp16 sup.
// ---------------------------------------------------------------------------
__global__ __launch_bounds__(256)
void agg2_kernel(const unsigned short* __restrict__ sup, const int2* __restrict__ rec,
                 const int* __restrict__ rowptr, const float* __restrict__ b2,
                 float* __restrict__ out, int n)
{
    int node = blockIdx.x * 4 + (threadIdx.x >> 6);
    int lane = threadIdx.x & 63;
    if (node >= n) return;

    int j   = rowptr[node];
    int end = rowptr[node + 1];
    float acc = 0.f;

    for (; j + 4 <= end; j += 4) {
        int2 r0 = rec[j];
        int2 r1 = rec[j + 1];
        int2 r2 = rec[j + 2];
        int2 r3 = rec[j + 3];
        unsigned short u0 = sup[(long long)r0.x * 64 + lane];
        unsigned short u1 = sup[(long long)r1.x * 64 + lane];
        unsigned short u2 = sup[(long long)r2.x * 64 + lane];
        unsigned short u3 = sup[(long long)r3.x * 64 + lane];
        acc = fmaf(__half2float(*(__half*)&u0), __int_as_float(r0.y), acc);
        acc = fmaf(__half2float(*(__half*)&u1), __int_as_float(r1.y), acc);
        acc = fmaf(__half2float(*(__half*)&u2), __int_as_float(r2.y), acc);
        acc = fmaf(__half2float(*(__half*)&u3), __int_as_float(r3.y), acc);
    }
    for (; j < end; j++) {
        int2 r0 = rec[j];
        unsigned short u0 = sup[(long long)r0.x * 64 + lane];
        acc = fmaf(__half2float(*(__half*)&u0), __int_as_float(r0.y), acc);
    }

    float v = acc + b2[lane];
    float m = v;
#pragma unroll
    for (int off = 32; off; off >>= 1) m = fmaxf(m, __shfl_xor(m, off, 64));
    float e = __expf(v - m);
    float s = e;
#pragma unroll
    for (int off = 32; off; off >>= 1) s += __shfl_xor(s, off, 64);
    out[(long long)node * 64 + lane] = e / s;
}

// ---------------------------------------------------------------------------
extern "C" void kernel_launch(void* const* d_in, const int* in_sizes, int n_in,
                              void* d_out, int out_size, void* d_ws, size_t ws_size,
                              hipStream_t stream)
{
    const float* y   = (const float*)d_in[0];   // [NN, F0]
    const int*   src = (const int*)  d_in[1];   // [NE]
    const int*   dst = (const int*)  d_in[2];   // [NE]
    const float* ew  = (const float*)d_in[3];   // [NE]
    const float* W1  = (const float*)d_in[4];   // [F0, F1]
    const float* b1  = (const float*)d_in[5];   // [F1]
    const float* W2  = (const float*)d_in[6];   // [F1, F2]
    const float* b2  = (const float*)d_in[7];   // [F2]

    float* out     = (float*)d_out;
    float* softout = out;                              // [NN, F2]
    float* h       = out + (size_t)NN * F2;            // [NN, F1] embedding

    // ---- workspace layout (256B-aligned chunks; total ~45.8 MB) ----
    char* ws = (char*)d_ws;
    size_t o = 0;
    auto alloc = [&](size_t bytes) -> void* {
        void* p = ws + o;
        o = (o + bytes + 255) & ~(size_t)255;
        return p;
    };
    unsigned short* sup  = (unsigned short*)alloc((size_t)NN * F1 * 2); // fp16, reused for layer2
    int2*           rec  = (int2*)          alloc((size_t)NE * 8);
    int*            rank = (int*)           alloc((size_t)NE * 4);
    int*            rowptr = (int*)         alloc((size_t)(NN + 2) * 4);
    int*            cnt  = (int*)           alloc((size_t)NN * 4);
    int*            bsum = (int*)           alloc(512 * 4);
    unsigned short* W1t  = (unsigned short*)alloc((size_t)F0 * F1 * 2);
    unsigned short* W2t  = (unsigned short*)alloc((size_t)F1 * F2 * 2);

    const int NB = (NN + 255) / 256;

    // ---- weights: transpose + bf16 convert ----
    wt_kernel<<<(F0 * F1 + F1 * F2 + 255) / 256, 256, 0, stream>>>(W1, W2, W1t, W2t);

    // ---- build dst-CSR (single atomic pass: rank recorded in hist) ----
    hipMemsetAsync(cnt, 0, (size_t)NN * 4, stream);
    hist_kernel<<<(NE + 255) / 256, 256, 0, stream>>>(dst, cnt, rank, NE);
    scan1_kernel<<<NB, 256, 0, stream>>>(cnt, rowptr, bsum, NN);
    scan2_kernel<<<1, 512, 0, stream>>>(bsum, NB, rowptr, NN, NE);
    scan3_kernel<<<NB, 256, 0, stream>>>(rowptr, bsum, NN);
    fill_kernel<<<(NE + 255) / 256, 256, 0, stream>>>(src, dst, ew, rowptr, rank, rec, NE);

    // ---- layer 1: support = y @ W1 (bf16 MFMA, fp16 out), then gather-agg ----
    mfma_gemm<128, 128, 64, 8>
        <<<(NN + 127) / 128, 256, 0, stream>>>(y, W1t, sup, NN, F0, F1);
    agg1_kernel<<<(NN + 3) / 4, 256, 0, stream>>>(
        (const unsigned int*)sup, rec, rowptr, (const float2*)b1, (float2*)h, NN);

    // ---- layer 2: support = h @ W2 (fp32 A converted, fp16 out), then agg+softmax ----
    mfma_gemm<128, 64, 64, 4>
        <<<(NN + 127) / 128, 256, 0, stream>>>(h, W2t, sup, NN, F1, F2);
    agg2_kernel<<<(NN + 3) / 4, 256, 0, stream>>>(
        sup, rec, rowptr, b2, softout, NN);
}

// Round 4
// 612.661 us; speedup vs baseline: 1.1864x; 1.0068x over previous
//
#include <hip/hip_runtime.h>
#include <hip/hip_fp16.h>

#define NN 100000      // nodes
#define NE 1600000     // edges
#define F0 512         // NFEAT
#define F1 128         // NHID
#define F2 64          // NCLASS

typedef short bf16x8 __attribute__((ext_vector_type(8)));
typedef float f32x4  __attribute__((ext_vector_type(4)));

// fp32 -> bf16 (round-to-nearest-even, finite inputs)
static __device__ __forceinline__ unsigned short f2bf(float f) {
    unsigned int u = __float_as_uint(f);
    return (unsigned short)((u + 0x7FFFu + ((u >> 16) & 1u)) >> 16);
}

// fp32 -> fp16 bits (RNE)
static __device__ __forceinline__ unsigned short f2h(float f) {
    __half h = __float2half(f);
    return *(unsigned short*)&h;
}

// packed 2xfp16 -> 2xfp32
static __device__ __forceinline__ float2 h2f2(unsigned int u) {
    __half2 h = *(__half2*)&u;
    return __half22float2(h);
}

// ---------------------------------------------------------------------------
// Pre-transpose + convert weights: W1[512,128] -> W1t[128,512] bf16,
//                                  W2[128,64]  -> W2t[64,128]  bf16.
// ---------------------------------------------------------------------------
__global__ __launch_bounds__(256)
void wt_kernel(const float* __restrict__ W1, const float* __restrict__ W2,
               unsigned short* __restrict__ W1t, unsigned short* __restrict__ W2t)
{
    int i = blockIdx.x * 256 + threadIdx.x;
    if (i < F0 * F1) {
        int n = i / F0, k = i % F0;
        W1t[i] = f2bf(W1[k * F1 + n]);
    } else {
        int j = i - F0 * F1;
        if (j < F1 * F2) {
            int n = j / F1, k = j % F1;
            W2t[j] = f2bf(W2[k * F2 + n]);
        }
    }
}

// ---------------------------------------------------------------------------
// bf16 MFMA GEMM (layer 1): C[M,N] = A[M,K] @ B[K,N], A fp32 (converted on
// the fly), B pre-transposed bf16 Bt[N,K]. N == BN. C: fp16.
// ---------------------------------------------------------------------------
template<int BM, int BN, int BK, int TN>
__global__ __launch_bounds__(256)
void mfma_gemm(const float* __restrict__ A, const unsigned short* __restrict__ Bt,
               unsigned short* __restrict__ C, int M, int K, int N)
{
    constexpr int LDA = BK + 8;   // pad: 72 shorts = 144 B = 36 banks
    constexpr int LDB = BK + 8;
    __shared__ unsigned short As[BM * LDA];
    __shared__ unsigned short Bs[BN * LDB];

    const int tid  = threadIdx.x;
    const int wave = tid >> 6;
    const int lane = tid & 63;
    const int lr   = lane & 15;
    const int quad = lane >> 4;
    const int row0 = blockIdx.x * BM;

    f32x4 acc[2][TN];
#pragma unroll
    for (int i = 0; i < 2; i++)
#pragma unroll
        for (int j = 0; j < TN; j++) acc[i][j] = (f32x4)0.f;

    for (int k0 = 0; k0 < K; k0 += BK) {
        // --- stage A tile (BM x BK) fp32 -> bf16 ---
#pragma unroll
        for (int l = tid; l < BM * (BK / 4); l += 256) {
            int m  = l / (BK / 4);
            int kq = l % (BK / 4);
            int rg = row0 + m; if (rg >= M) rg = M - 1;
            float4 v = *(const float4*)(A + (long long)rg * K + k0 + kq * 4);
            ushort4 b = make_ushort4(f2bf(v.x), f2bf(v.y), f2bf(v.z), f2bf(v.w));
            *(ushort4*)(&As[m * LDA + kq * 4]) = b;
        }
        // --- stage B tile (BN x BK) from Bt[N,K] (already bf16) ---
#pragma unroll
        for (int l = tid; l < BN * (BK / 8); l += 256) {
            int n  = l / (BK / 8);
            int ko = l % (BK / 8);
            uint4 v = *(const uint4*)(Bt + (long long)n * K + k0 + ko * 8);
            *(uint4*)(&Bs[n * LDB + ko * 8]) = v;
        }
        __syncthreads();

#pragma unroll
        for (int kk = 0; kk < BK; kk += 32) {
            bf16x8 a[2], b[TN];
#pragma unroll
            for (int tm = 0; tm < 2; tm++)
                a[tm] = *(const bf16x8*)(&As[(wave * 32 + tm * 16 + lr) * LDA + kk + quad * 8]);
#pragma unroll
            for (int tn = 0; tn < TN; tn++)
                b[tn] = *(const bf16x8*)(&Bs[(tn * 16 + lr) * LDB + kk + quad * 8]);
#pragma unroll
            for (int tm = 0; tm < 2; tm++)
#pragma unroll
                for (int tn = 0; tn < TN; tn++)
                    acc[tm][tn] = __builtin_amdgcn_mfma_f32_16x16x32_bf16(
                        a[tm], b[tn], acc[tm][tn], 0, 0, 0);
        }
        __syncthreads();
    }

    // --- epilogue: C/D layout col=lane&15, row=quad*4+reg; store fp16 ---
#pragma unroll
    for (int tm = 0; tm < 2; tm++) {
#pragma unroll
        for (int r = 0; r < 4; r++) {
            int row = row0 + wave * 32 + tm * 16 + quad * 4 + r;
            if (row < M) {
#pragma unroll
                for (int tn = 0; tn < TN; tn++)
                    C[(long long)row * N + tn * 16 + lr] = f2h(acc[tm][tn][r]);
            }
        }
    }
}

// ---------------------------------------------------------------------------
// CSR build: histogram+rank, 3-phase exclusive scan, fill (no 2nd atomic pass)
// ---------------------------------------------------------------------------
__global__ __launch_bounds__(256)
void hist_kernel(const int* __restrict__ dst, int* __restrict__ cnt,
                 int* __restrict__ rank, int ne)
{
    int e = blockIdx.x * 256 + threadIdx.x;
    if (e < ne) rank[e] = atomicAdd(&cnt[dst[e]], 1);
}

__global__ __launch_bounds__(256)
void scan1_kernel(const int* __restrict__ cnt, int* __restrict__ rowptr,
                  int* __restrict__ bsum, int n)
{
    __shared__ int s[256];
    int t = threadIdx.x;
    int i = blockIdx.x * 256 + t;
    int v = (i < n) ? cnt[i] : 0;
    s[t] = v;
    __syncthreads();
#pragma unroll
    for (int off = 1; off < 256; off <<= 1) {
        int x = (t >= off) ? s[t - off] : 0;
        __syncthreads();
        s[t] += x;
        __syncthreads();
    }
    if (i < n) rowptr[i] = s[t] - v;
    if (t == 255) bsum[blockIdx.x] = s[255];
}

__global__ __launch_bounds__(512)
void scan2_kernel(int* __restrict__ bsum, int nb, int* __restrict__ rowptr, int n, int ne)
{
    __shared__ int s[512];
    int t = threadIdx.x;
    int v = (t < nb) ? bsum[t] : 0;
    s[t] = v;
    __syncthreads();
#pragma unroll
    for (int off = 1; off < 512; off <<= 1) {
        int x = (t >= off) ? s[t - off] : 0;
        __syncthreads();
        s[t] += x;
        __syncthreads();
    }
    if (t < nb) bsum[t] = s[t] - v;
    if (t == 0) rowptr[n] = ne;
}

__global__ __launch_bounds__(256)
void scan3_kernel(int* __restrict__ rowptr, const int* __restrict__ bsum, int n)
{
    int i = blockIdx.x * 256 + threadIdx.x;
    if (i < n) rowptr[i] += bsum[i >> 8];
}

__global__ __launch_bounds__(256)
void fill_kernel(const int* __restrict__ src, const int* __restrict__ dst,
                 const float* __restrict__ ew, const int* __restrict__ rowptr,
                 const int* __restrict__ rank, int2* __restrict__ rec, int ne)
{
    int e = blockIdx.x * 256 + threadIdx.x;
    if (e >= ne) return;
    int d = dst[e];
    int pos = rowptr[d] + rank[e];
    rec[pos] = make_int2(src[e], __float_as_int(ew[e]));
}

// ---------------------------------------------------------------------------
// Fused aggregation layer 1 + gemm2: 16 nodes/block, 4 waves, 4 nodes/wave.
// Per node: gather-agg over fp16 sup rows -> bias -> leaky-relu -> write fp32 h
// and drop bf16 h-row into LDS. Then each wave does h@W2 for a 16-col slab
// via 4 MFMAs (A from LDS, B = W2t rows from global, L2-hot) -> fp16 sup2.
// Numerically identical to the previous separate gemm2 (same f2bf(h) @ W2t).
// ---------------------------------------------------------------------------
__global__ __launch_bounds__(256)
void agg1_fused_kernel(const unsigned int* __restrict__ sup, const int2* __restrict__ rec,
                       const int* __restrict__ rowptr, const float2* __restrict__ b1,
                       const unsigned short* __restrict__ W2t,
                       float2* __restrict__ h, unsigned short* __restrict__ sup2, int n)
{
    constexpr int LDH = F1 + 8;                 // 136 shorts = 272 B
    __shared__ unsigned short hsb[16 * LDH];    // 4.25 KB

    const int tid  = threadIdx.x;
    const int w    = tid >> 6;
    const int lane = tid & 63;
    const int base = blockIdx.x * 16;

    float2 bb = b1[lane];

#pragma unroll
    for (int i = 0; i < 4; i++) {
        int row  = w * 4 + i;
        int node = base + row;
        float2 acc = make_float2(0.f, 0.f);
        if (node < n) {
            int j   = rowptr[node];
            int end = rowptr[node + 1];
            for (; j + 4 <= end; j += 4) {
                int2 r0 = rec[j];
                int2 r1 = rec[j + 1];
                int2 r2 = rec[j + 2];
                int2 r3 = rec[j + 3];
                unsigned int u0 = sup[(long long)r0.x * 64 + lane];
                unsigned int u1 = sup[(long long)r1.x * 64 + lane];
                unsigned int u2 = sup[(long long)r2.x * 64 + lane];
                unsigned int u3 = sup[(long long)r3.x * 64 + lane];
                float w0 = __int_as_float(r0.y);
                float w1 = __int_as_float(r1.y);
                float w2 = __int_as_float(r2.y);
                float w3 = __int_as_float(r3.y);
                float2 f0 = h2f2(u0);
                float2 f1 = h2f2(u1);
                float2 f2 = h2f2(u2);
                float2 f3 = h2f2(u3);
                acc.x = fmaf(f0.x, w0, acc.x);  acc.y = fmaf(f0.y, w0, acc.y);
                acc.x = fmaf(f1.x, w1, acc.x);  acc.y = fmaf(f1.y, w1, acc.y);
                acc.x = fmaf(f2.x, w2, acc.x);  acc.y = fmaf(f2.y, w2, acc.y);
                acc.x = fmaf(f3.x, w3, acc.x);  acc.y = fmaf(f3.y, w3, acc.y);
            }
            for (; j < end; j++) {
                int2 r0 = rec[j];
                unsigned int u0 = sup[(long long)r0.x * 64 + lane];
                float w0 = __int_as_float(r0.y);
                float2 f0 = h2f2(u0);
                acc.x = fmaf(f0.x, w0, acc.x);
                acc.y = fmaf(f0.y, w0, acc.y);
            }
            acc.x += bb.x;
            acc.y += bb.y;
            acc.x = acc.x > 0.f ? acc.x : 0.01f * acc.x;
            acc.y = acc.y > 0.f ? acc.y : 0.01f * acc.y;
            h[(long long)node * 64 + lane] = acc;
        }
        ushort2 hv = (node < n) ? make_ushort2(f2bf(acc.x), f2bf(acc.y))
                                : make_ushort2(0, 0);
        *(ushort2*)(&hsb[row * LDH + lane * 2]) = hv;
    }
    __syncthreads();

    // --- h @ W2 for this block's 16 nodes; wave w -> cols [w*16, w*16+16) ---
    const int lr   = lane & 15;
    const int quad = lane >> 4;
    f32x4 acc2 = (f32x4)0.f;
#pragma unroll
    for (int kk = 0; kk < F1; kk += 32) {
        bf16x8 a = *(const bf16x8*)(&hsb[lr * LDH + kk + quad * 8]);
        bf16x8 b = *(const bf16x8*)(W2t + (w * 16 + lr) * F1 + kk + quad * 8);
        acc2 = __builtin_amdgcn_mfma_f32_16x16x32_bf16(a, b, acc2, 0, 0, 0);
    }
#pragma unroll
    for (int r = 0; r < 4; r++) {
        int node = base + quad * 4 + r;
        if (node < n)
            sup2[(long long)node * 64 + w * 16 + lr] = f2h(acc2[r]);
    }
}

// ---------------------------------------------------------------------------
// Fused aggregation layer 2 + softmax: one wave per node (F2=64), fp16 sup2.
// ---------------------------------------------------------------------------
__global__ __launch_bounds__(256)
void agg2_kernel(const unsigned short* __restrict__ sup, const int2* __restrict__ rec,
                 const int* __restrict__ rowptr, const float* __restrict__ b2,
                 float* __restrict__ out, int n)
{
    int node = blockIdx.x * 4 + (threadIdx.x >> 6);
    int lane = threadIdx.x & 63;
    if (node >= n) return;

    int j   = rowptr[node];
    int end = rowptr[node + 1];
    float acc = 0.f;

    for (; j + 4 <= end; j += 4) {
        int2 r0 = rec[j];
        int2 r1 = rec[j + 1];
        int2 r2 = rec[j + 2];
        int2 r3 = rec[j + 3];
        unsigned short u0 = sup[(long long)r0.x * 64 + lane];
        unsigned short u1 = sup[(long long)r1.x * 64 + lane];
        unsigned short u2 = sup[(long long)r2.x * 64 + lane];
        unsigned short u3 = sup[(long long)r3.x * 64 + lane];
        acc = fmaf(__half2float(*(__half*)&u0), __int_as_float(r0.y), acc);
        acc = fmaf(__half2float(*(__half*)&u1), __int_as_float(r1.y), acc);
        acc = fmaf(__half2float(*(__half*)&u2), __int_as_float(r2.y), acc);
        acc = fmaf(__half2float(*(__half*)&u3), __int_as_float(r3.y), acc);
    }
    for (; j < end; j++) {
        int2 r0 = rec[j];
        unsigned short u0 = sup[(long long)r0.x * 64 + lane];
        acc = fmaf(__half2float(*(__half*)&u0), __int_as_float(r0.y), acc);
    }

    float v = acc + b2[lane];
    float m = v;
#pragma unroll
    for (int off = 32; off; off >>= 1) m = fmaxf(m, __shfl_xor(m, off, 64));
    float e = __expf(v - m);
    float s = e;
#pragma unroll
    for (int off = 32; off; off >>= 1) s += __shfl_xor(s, off, 64);
    out[(long long)node * 64 + lane] = e / s;
}

// ---------------------------------------------------------------------------
extern "C" void kernel_launch(void* const* d_in, const int* in_sizes, int n_in,
                              void* d_out, int out_size, void* d_ws, size_t ws_size,
                              hipStream_t stream)
{
    const float* y   = (const float*)d_in[0];   // [NN, F0]
    const int*   src = (const int*)  d_in[1];   // [NE]
    const int*   dst = (const int*)  d_in[2];   // [NE]
    const float* ew  = (const float*)d_in[3];   // [NE]
    const float* W1  = (const float*)d_in[4];   // [F0, F1]
    const float* b1  = (const float*)d_in[5];   // [F1]
    const float* W2  = (const float*)d_in[6];   // [F1, F2]
    const float* b2  = (const float*)d_in[7];   // [F2]

    float* out     = (float*)d_out;
    float* softout = out;                              // [NN, F2]
    float* h       = out + (size_t)NN * F2;            // [NN, F1] embedding

    // ---- workspace layout (256B-aligned chunks; total ~58.6 MB) ----
    char* ws = (char*)d_ws;
    size_t o = 0;
    auto alloc = [&](size_t bytes) -> void* {
        void* p = ws + o;
        o = (o + bytes + 255) & ~(size_t)255;
        return p;
    };
    unsigned short* sup  = (unsigned short*)alloc((size_t)NN * F1 * 2); // fp16 layer-1 support
    unsigned short* sup2 = (unsigned short*)alloc((size_t)NN * F2 * 2); // fp16 layer-2 support
    int2*           rec  = (int2*)          alloc((size_t)NE * 8);
    int*            rank = (int*)           alloc((size_t)NE * 4);
    int*            rowptr = (int*)         alloc((size_t)(NN + 2) * 4);
    int*            cnt  = (int*)           alloc((size_t)NN * 4);
    int*            bsum = (int*)           alloc(512 * 4);
    unsigned short* W1t  = (unsigned short*)alloc((size_t)F0 * F1 * 2);
    unsigned short* W2t  = (unsigned short*)alloc((size_t)F1 * F2 * 2);

    const int NB = (NN + 255) / 256;

    // ---- weights: transpose + bf16 convert ----
    wt_kernel<<<(F0 * F1 + F1 * F2 + 255) / 256, 256, 0, stream>>>(W1, W2, W1t, W2t);

    // ---- build dst-CSR (single atomic pass: rank recorded in hist) ----
    hipMemsetAsync(cnt, 0, (size_t)NN * 4, stream);
    hist_kernel<<<(NE + 255) / 256, 256, 0, stream>>>(dst, cnt, rank, NE);
    scan1_kernel<<<NB, 256, 0, stream>>>(cnt, rowptr, bsum, NN);
    scan2_kernel<<<1, 512, 0, stream>>>(bsum, NB, rowptr, NN, NE);
    scan3_kernel<<<NB, 256, 0, stream>>>(rowptr, bsum, NN);
    fill_kernel<<<(NE + 255) / 256, 256, 0, stream>>>(src, dst, ew, rowptr, rank, rec, NE);

    // ---- layer 1: support = y @ W1 (bf16 MFMA, fp16 out) ----
    mfma_gemm<128, 128, 64, 8>
        <<<(NN + 127) / 128, 256, 0, stream>>>(y, W1t, sup, NN, F0, F1);

    // ---- fused: gather-agg + bias + leaky-relu -> h; h @ W2 -> sup2 ----
    agg1_fused_kernel<<<(NN + 15) / 16, 256, 0, stream>>>(
        (const unsigned int*)sup, rec, rowptr, (const float2*)b1, W2t,
        (float2*)h, sup2, NN);

    // ---- layer 2 aggregation + softmax ----
    agg2_kernel<<<(NN + 3) / 4, 256, 0, stream>>>(
        sup2, rec, rowptr, b2, softout, NN);
}

// Round 5
// 570.899 us; speedup vs baseline: 1.2732x; 1.0732x over previous
//
#include <hip/hip_runtime.h>
#include <hip/hip_fp16.h>

#define NN 100000      // nodes
#define NE 1600000     // edges
#define F0 512         // NFEAT
#define F1 128         // NHID
#define F2 64          // NCLASS

typedef short bf16x8 __attribute__((ext_vector_type(8)));
typedef float f32x4  __attribute__((ext_vector_type(4)));

// fp32 -> bf16 (round-to-nearest-even, finite inputs)
static __device__ __forceinline__ unsigned short f2bf(float f) {
    unsigned int u = __float_as_uint(f);
    return (unsigned short)((u + 0x7FFFu + ((u >> 16) & 1u)) >> 16);
}

// fp32 -> fp16 bits (RNE)
static __device__ __forceinline__ unsigned short f2h(float f) {
    __half h = __float2half(f);
    return *(unsigned short*)&h;
}

// packed 2xfp16 -> 2xfp32
static __device__ __forceinline__ float2 h2f2(unsigned int u) {
    __half2 h = *(__half2*)&u;
    return __half22float2(h);
}

// ---------------------------------------------------------------------------
// Pre-transpose + convert weights: W1[512,128] -> W1t[128,512] bf16,
//                                  W2[128,64]  -> W2t[64,128]  bf16.
// ---------------------------------------------------------------------------
__global__ __launch_bounds__(256)
void wt_kernel(const float* __restrict__ W1, const float* __restrict__ W2,
               unsigned short* __restrict__ W1t, unsigned short* __restrict__ W2t)
{
    int i = blockIdx.x * 256 + threadIdx.x;
    if (i < F0 * F1) {
        int n = i / F0, k = i % F0;
        W1t[i] = f2bf(W1[k * F1 + n]);
    } else {
        int j = i - F0 * F1;
        if (j < F1 * F2) {
            int n = j / F1, k = j % F1;
            W2t[j] = f2bf(W2[k * F2 + n]);
        }
    }
}

// ---------------------------------------------------------------------------
// Merged dispatch: blocks [0, gemm_blocks) run a slice of the bf16 MFMA GEMM
// (C[M,N] = A@B, A fp32 converted on the fly, B = Bt[N,K] bf16, C fp16);
// blocks [gemm_blocks, ...) run an independent edge task:
//   FILL=false: rank[e] = atomicAdd(&cnt[dst[e]], 1)      (histogram)
//   FILL=true : rec[rowptr[dst[e]] + rank[e]] = {src,w}   (CSR fill)
// The edge task has no dependency on the GEMM slice -> they overlap across CUs.
// ---------------------------------------------------------------------------
template<int BM, int BN, int BK, int TN, bool FILL>
__global__ __launch_bounds__(256)
void gemm_edge_kernel(const float* __restrict__ A, const unsigned short* __restrict__ Bt,
                      unsigned short* __restrict__ C, int M, int K, int N,
                      int row_base, int gemm_blocks,
                      const int* __restrict__ src, const int* __restrict__ dst,
                      const float* __restrict__ ew, const int* __restrict__ rowptr,
                      int* __restrict__ cnt, int* __restrict__ rank,
                      int2* __restrict__ rec, int ne)
{
    constexpr int LDA = BK + 8;   // pad: 72 shorts = 144 B = 36 banks
    constexpr int LDB = BK + 8;
    __shared__ unsigned short As[BM * LDA];
    __shared__ unsigned short Bs[BN * LDB];

    if ((int)blockIdx.x >= gemm_blocks) {
        // ---- edge task ----
        int e = ((int)blockIdx.x - gemm_blocks) * 256 + threadIdx.x;
        if (e < ne) {
            if constexpr (!FILL) {
                rank[e] = atomicAdd(&cnt[dst[e]], 1);
            } else {
                int d = dst[e];
                int pos = rowptr[d] + rank[e];
                rec[pos] = make_int2(src[e], __float_as_int(ew[e]));
            }
        }
        return;
    }

    // ---- GEMM slice ----
    const int tid  = threadIdx.x;
    const int wave = tid >> 6;
    const int lane = tid & 63;
    const int lr   = lane & 15;
    const int quad = lane >> 4;
    const int row0 = row_base + (int)blockIdx.x * BM;

    f32x4 acc[2][TN];
#pragma unroll
    for (int i = 0; i < 2; i++)
#pragma unroll
        for (int j = 0; j < TN; j++) acc[i][j] = (f32x4)0.f;

    for (int k0 = 0; k0 < K; k0 += BK) {
        // --- stage A tile (BM x BK) fp32 -> bf16 ---
#pragma unroll
        for (int l = tid; l < BM * (BK / 4); l += 256) {
            int m  = l / (BK / 4);
            int kq = l % (BK / 4);
            int rg = row0 + m; if (rg >= M) rg = M - 1;
            float4 v = *(const float4*)(A + (long long)rg * K + k0 + kq * 4);
            ushort4 b = make_ushort4(f2bf(v.x), f2bf(v.y), f2bf(v.z), f2bf(v.w));
            *(ushort4*)(&As[m * LDA + kq * 4]) = b;
        }
        // --- stage B tile (BN x BK) from Bt[N,K] (already bf16) ---
#pragma unroll
        for (int l = tid; l < BN * (BK / 8); l += 256) {
            int n  = l / (BK / 8);
            int ko = l % (BK / 8);
            uint4 v = *(const uint4*)(Bt + (long long)n * K + k0 + ko * 8);
            *(uint4*)(&Bs[n * LDB + ko * 8]) = v;
        }
        __syncthreads();

#pragma unroll
        for (int kk = 0; kk < BK; kk += 32) {
            bf16x8 a[2], b[TN];
#pragma unroll
            for (int tm = 0; tm < 2; tm++)
                a[tm] = *(const bf16x8*)(&As[(wave * 32 + tm * 16 + lr) * LDA + kk + quad * 8]);
#pragma unroll
            for (int tn = 0; tn < TN; tn++)
                b[tn] = *(const bf16x8*)(&Bs[(tn * 16 + lr) * LDB + kk + quad * 8]);
#pragma unroll
            for (int tm = 0; tm < 2; tm++)
#pragma unroll
                for (int tn = 0; tn < TN; tn++)
                    acc[tm][tn] = __builtin_amdgcn_mfma_f32_16x16x32_bf16(
                        a[tm], b[tn], acc[tm][tn], 0, 0, 0);
        }
        __syncthreads();
    }

    // --- epilogue: C/D layout col=lane&15, row=quad*4+reg; store fp16 ---
#pragma unroll
    for (int tm = 0; tm < 2; tm++) {
#pragma unroll
        for (int r = 0; r < 4; r++) {
            int row = row0 + wave * 32 + tm * 16 + quad * 4 + r;
            if (row < M) {
#pragma unroll
                for (int tn = 0; tn < TN; tn++)
                    C[(long long)row * N + tn * 16 + lr] = f2h(acc[tm][tn][r]);
            }
        }
    }
}

// ---------------------------------------------------------------------------
// CSR scan (3-phase exclusive)
// ---------------------------------------------------------------------------
__global__ __launch_bounds__(256)
void scan1_kernel(const int* __restrict__ cnt, int* __restrict__ rowptr,
                  int* __restrict__ bsum, int n)
{
    __shared__ int s[256];
    int t = threadIdx.x;
    int i = blockIdx.x * 256 + t;
    int v = (i < n) ? cnt[i] : 0;
    s[t] = v;
    __syncthreads();
#pragma unroll
    for (int off = 1; off < 256; off <<= 1) {
        int x = (t >= off) ? s[t - off] : 0;
        __syncthreads();
        s[t] += x;
        __syncthreads();
    }
    if (i < n) rowptr[i] = s[t] - v;
    if (t == 255) bsum[blockIdx.x] = s[255];
}

__global__ __launch_bounds__(512)
void scan2_kernel(int* __restrict__ bsum, int nb, int* __restrict__ rowptr, int n, int ne)
{
    __shared__ int s[512];
    int t = threadIdx.x;
    int v = (t < nb) ? bsum[t] : 0;
    s[t] = v;
    __syncthreads();
#pragma unroll
    for (int off = 1; off < 512; off <<= 1) {
        int x = (t >= off) ? s[t - off] : 0;
        __syncthreads();
        s[t] += x;
        __syncthreads();
    }
    if (t < nb) bsum[t] = s[t] - v;
    if (t == 0) rowptr[n] = ne;
}

__global__ __launch_bounds__(256)
void scan3_kernel(int* __restrict__ rowptr, const int* __restrict__ bsum, int n)
{
    int i = blockIdx.x * 256 + threadIdx.x;
    if (i < n) rowptr[i] += bsum[i >> 8];
}

// ---------------------------------------------------------------------------
// Fused aggregation layer 1 + gemm2: 16 nodes/block, 4 waves, 4 nodes/wave.
// Gather loop unrolled 8-deep for outstanding-load ILP.
// ---------------------------------------------------------------------------
__global__ __launch_bounds__(256)
void agg1_fused_kernel(const unsigned int* __restrict__ sup, const int2* __restrict__ rec,
                       const int* __restrict__ rowptr, const float2* __restrict__ b1,
                       const unsigned short* __restrict__ W2t,
                       float2* __restrict__ h, unsigned short* __restrict__ sup2, int n)
{
    constexpr int LDH = F1 + 8;                 // 136 shorts = 272 B
    __shared__ unsigned short hsb[16 * LDH];    // 4.25 KB

    const int tid  = threadIdx.x;
    const int w    = tid >> 6;
    const int lane = tid & 63;
    const int base = blockIdx.x * 16;

    float2 bb = b1[lane];

#pragma unroll
    for (int i = 0; i < 4; i++) {
        int row  = w * 4 + i;
        int node = base + row;
        float2 acc = make_float2(0.f, 0.f);
        if (node < n) {
            int j   = rowptr[node];
            int end = rowptr[node + 1];
            for (; j + 8 <= end; j += 8) {
                int2 r[8];
#pragma unroll
                for (int u = 0; u < 8; u++) r[u] = rec[j + u];
                unsigned int uu[8];
#pragma unroll
                for (int u = 0; u < 8; u++)
                    uu[u] = sup[(long long)r[u].x * 64 + lane];
#pragma unroll
                for (int u = 0; u < 8; u++) {
                    float2 f = h2f2(uu[u]);
                    float  ww = __int_as_float(r[u].y);
                    acc.x = fmaf(f.x, ww, acc.x);
                    acc.y = fmaf(f.y, ww, acc.y);
                }
            }
            for (; j + 2 <= end; j += 2) {
                int2 r0 = rec[j];
                int2 r1 = rec[j + 1];
                unsigned int u0 = sup[(long long)r0.x * 64 + lane];
                unsigned int u1 = sup[(long long)r1.x * 64 + lane];
                float2 f0 = h2f2(u0);
                float2 f1 = h2f2(u1);
                float w0 = __int_as_float(r0.y);
                float w1 = __int_as_float(r1.y);
                acc.x = fmaf(f0.x, w0, acc.x);  acc.y = fmaf(f0.y, w0, acc.y);
                acc.x = fmaf(f1.x, w1, acc.x);  acc.y = fmaf(f1.y, w1, acc.y);
            }
            if (j < end) {
                int2 r0 = rec[j];
                unsigned int u0 = sup[(long long)r0.x * 64 + lane];
                float2 f0 = h2f2(u0);
                float w0 = __int_as_float(r0.y);
                acc.x = fmaf(f0.x, w0, acc.x);
                acc.y = fmaf(f0.y, w0, acc.y);
            }
            acc.x += bb.x;
            acc.y += bb.y;
            acc.x = acc.x > 0.f ? acc.x : 0.01f * acc.x;
            acc.y = acc.y > 0.f ? acc.y : 0.01f * acc.y;
            h[(long long)node * 64 + lane] = acc;
        }
        ushort2 hv = (node < n) ? make_ushort2(f2bf(acc.x), f2bf(acc.y))
                                : make_ushort2(0, 0);
        *(ushort2*)(&hsb[row * LDH + lane * 2]) = hv;
    }
    __syncthreads();

    // --- h @ W2 for this block's 16 nodes; wave w -> cols [w*16, w*16+16) ---
    const int lr   = lane & 15;
    const int quad = lane >> 4;
    f32x4 acc2 = (f32x4)0.f;
#pragma unroll
    for (int kk = 0; kk < F1; kk += 32) {
        bf16x8 a = *(const bf16x8*)(&hsb[lr * LDH + kk + quad * 8]);
        bf16x8 b = *(const bf16x8*)(W2t + (w * 16 + lr) * F1 + kk + quad * 8);
        acc2 = __builtin_amdgcn_mfma_f32_16x16x32_bf16(a, b, acc2, 0, 0, 0);
    }
#pragma unroll
    for (int r = 0; r < 4; r++) {
        int node = base + quad * 4 + r;
        if (node < n)
            sup2[(long long)node * 64 + w * 16 + lr] = f2h(acc2[r]);
    }
}

// ---------------------------------------------------------------------------
// Fused aggregation layer 2 + softmax: one wave per node (F2=64), fp16 sup2.
// Gather loop unrolled 8-deep.
// ---------------------------------------------------------------------------
__global__ __launch_bounds__(256)
void agg2_kernel(const unsigned short* __restrict__ sup, const int2* __restrict__ rec,
                 const int* __restrict__ rowptr, const float* __restrict__ b2,
                 float* __restrict__ out, int n)
{
    int node = blockIdx.x * 4 + (threadIdx.x >> 6);
    int lane = threadIdx.x & 63;
    if (node >= n) return;

    int j   = rowptr[node];
    int end = rowptr[node + 1];
    float acc = 0.f;

    for (; j + 8 <= end; j += 8) {
        int2 r[8];
#pragma unroll
        for (int u = 0; u < 8; u++) r[u] = rec[j + u];
        unsigned short uu[8];
#pragma unroll
        for (int u = 0; u < 8; u++)
            uu[u] = sup[(long long)r[u].x * 64 + lane];
#pragma unroll
        for (int u = 0; u < 8; u++)
            acc = fmaf(__half2float(*(__half*)&uu[u]), __int_as_float(r[u].y), acc);
    }
    for (; j + 2 <= end; j += 2) {
        int2 r0 = rec[j];
        int2 r1 = rec[j + 1];
        unsigned short u0 = sup[(long long)r0.x * 64 + lane];
        unsigned short u1 = sup[(long long)r1.x * 64 + lane];
        acc = fmaf(__half2float(*(__half*)&u0), __int_as_float(r0.y), acc);
        acc = fmaf(__half2float(*(__half*)&u1), __int_as_float(r1.y), acc);
    }
    if (j < end) {
        int2 r0 = rec[j];
        unsigned short u0 = sup[(long long)r0.x * 64 + lane];
        acc = fmaf(__half2float(*(__half*)&u0), __int_as_float(r0.y), acc);
    }

    float v = acc + b2[lane];
    float m = v;
#pragma unroll
    for (int off = 32; off; off >>= 1) m = fmaxf(m, __shfl_xor(m, off, 64));
    float e = __expf(v - m);
    float s = e;
#pragma unroll
    for (int off = 32; off; off >>= 1) s += __shfl_xor(s, off, 64);
    out[(long long)node * 64 + lane] = e / s;
}

// ---------------------------------------------------------------------------
extern "C" void kernel_launch(void* const* d_in, const int* in_sizes, int n_in,
                              void* d_out, int out_size, void* d_ws, size_t ws_size,
                              hipStream_t stream)
{
    const float* y   = (const float*)d_in[0];   // [NN, F0]
    const int*   src = (const int*)  d_in[1];   // [NE]
    const int*   dst = (const int*)  d_in[2];   // [NE]
    const float* ew  = (const float*)d_in[3];   // [NE]
    const float* W1  = (const float*)d_in[4];   // [F0, F1]
    const float* b1  = (const float*)d_in[5];   // [F1]
    const float* W2  = (const float*)d_in[6];   // [F1, F2]
    const float* b2  = (const float*)d_in[7];   // [F2]

    float* out     = (float*)d_out;
    float* softout = out;                              // [NN, F2]
    float* h       = out + (size_t)NN * F2;            // [NN, F1] embedding

    // ---- workspace layout (256B-aligned chunks; total ~58.6 MB) ----
    char* ws = (char*)d_ws;
    size_t o = 0;
    auto alloc = [&](size_t bytes) -> void* {
        void* p = ws + o;
        o = (o + bytes + 255) & ~(size_t)255;
        return p;
    };
    unsigned short* sup  = (unsigned short*)alloc((size_t)NN * F1 * 2); // fp16 layer-1 support
    unsigned short* sup2 = (unsigned short*)alloc((size_t)NN * F2 * 2); // fp16 layer-2 support
    int2*           rec  = (int2*)          alloc((size_t)NE * 8);
    int*            rank = (int*)           alloc((size_t)NE * 4);
    int*            rowptr = (int*)         alloc((size_t)(NN + 2) * 4);
    int*            cnt  = (int*)           alloc((size_t)NN * 4);
    int*            bsum = (int*)           alloc(512 * 4);
    unsigned short* W1t  = (unsigned short*)alloc((size_t)F0 * F1 * 2);
    unsigned short* W2t  = (unsigned short*)alloc((size_t)F1 * F2 * 2);

    const int NB = (NN + 255) / 256;          // 391 scan blocks
    const int GB = (NN + 127) / 128;          // 782 gemm1 blocks total
    const int GA = GB / 2;                    // 391 first-half blocks
    const int EB = (NE + 255) / 256;          // 6250 edge blocks

    // ---- weights: transpose + bf16 convert; zero counters ----
    hipMemsetAsync(cnt, 0, (size_t)NN * 4, stream);
    wt_kernel<<<(F0 * F1 + F1 * F2 + 255) / 256, 256, 0, stream>>>(W1, W2, W1t, W2t);

    // ---- [gemm1 first half || histogram+rank] ----
    gemm_edge_kernel<128, 128, 64, 8, false><<<GA + EB, 256, 0, stream>>>(
        y, W1t, sup, NN, F0, F1, /*row_base=*/0, /*gemm_blocks=*/GA,
        src, dst, ew, rowptr, cnt, rank, rec, NE);

    // ---- CSR scan ----
    scan1_kernel<<<NB, 256, 0, stream>>>(cnt, rowptr, bsum, NN);
    scan2_kernel<<<1, 512, 0, stream>>>(bsum, NB, rowptr, NN, NE);
    scan3_kernel<<<NB, 256, 0, stream>>>(rowptr, bsum, NN);

    // ---- [gemm1 second half || CSR fill] ----
    gemm_edge_kernel<128, 128, 64, 8, true><<<(GB - GA) + EB, 256, 0, stream>>>(
        y, W1t, sup, NN, F0, F1, /*row_base=*/GA * 128, /*gemm_blocks=*/GB - GA,
        src, dst, ew, rowptr, cnt, rank, rec, NE);

    // ---- fused: gather-agg + bias + leaky-relu -> h; h @ W2 -> sup2 ----
    agg1_fused_kernel<<<(NN + 15) / 16, 256, 0, stream>>>(
        (const unsigned int*)sup, rec, rowptr, (const float2*)b1, W2t,
        (float2*)h, sup2, NN);

    // ---- layer 2 aggregation + softmax ----
    agg2_kernel<<<(NN + 3) / 4, 256, 0, stream>>>(
        sup2, rec, rowptr, b2, softout, NN);
}

// Round 7
// 553.192 us; speedup vs baseline: 1.3140x; 1.0320x over previous
//
#include <hip/hip_runtime.h>
#include <hip/hip_fp16.h>

#define NN 100000      // nodes
#define NE 1600000     // edges
#define F0 512         // NFEAT
#define F1 128         // NHID
#define F2 64          // NCLASS

typedef short bf16x8 __attribute__((ext_vector_type(8)));
typedef float f32x4  __attribute__((ext_vector_type(4)));

// fp32 -> bf16 (round-to-nearest-even, finite inputs)
static __device__ __forceinline__ unsigned short f2bf(float f) {
    unsigned int u = __float_as_uint(f);
    return (unsigned short)((u + 0x7FFFu + ((u >> 16) & 1u)) >> 16);
}

// fp32 -> fp16 bits (RNE)
static __device__ __forceinline__ unsigned short f2h(float f) {
    __half h = __float2half(f);
    return *(unsigned short*)&h;
}

// packed 2xfp16 -> 2xfp32
static __device__ __forceinline__ float2 h2f2(unsigned int u) {
    __half2 h = *(__half2*)&u;
    return __half22float2(h);
}

// ---------------------------------------------------------------------------
// Weights transpose+convert AND cnt zeroing in one launch (391 blocks).
// ---------------------------------------------------------------------------
__global__ __launch_bounds__(256)
void wt_kernel(const float* __restrict__ W1, const float* __restrict__ W2,
               unsigned short* __restrict__ W1t, unsigned short* __restrict__ W2t,
               int* __restrict__ cnt, int grid_threads)
{
    int i = blockIdx.x * 256 + threadIdx.x;
    if (i < F0 * F1) {
        int n = i / F0, k = i % F0;
        W1t[i] = f2bf(W1[k * F1 + n]);
    } else {
        int j = i - F0 * F1;
        if (j < F1 * F2) {
            int n = j / F1, k = j % F1;
            W2t[j] = f2bf(W2[k * F2 + n]);
        }
    }
    for (int z = i; z < NN + 256; z += grid_threads) cnt[z] = 0;
}

// ---------------------------------------------------------------------------
// Merged dispatch: blocks [0, gemm_blocks) run a slice of the bf16 MFMA GEMM;
// blocks [gemm_blocks, ...) run an independent edge task:
//   FILL=false: rank[e] = atomicAdd(&cnt[dst[e]], 1)                (histogram)
//   FILL=true : rec[rowptr[d]+bsum[d>>8]+rank[e]] = {src,w}         (CSR fill)
// ---------------------------------------------------------------------------
template<int BM, int BN, int BK, int TN, bool FILL>
__global__ __launch_bounds__(256)
void gemm_edge_kernel(const float* __restrict__ A, const unsigned short* __restrict__ Bt,
                      unsigned short* __restrict__ C, int M, int K, int N,
                      int row_base, int gemm_blocks,
                      const int* __restrict__ src, const int* __restrict__ dst,
                      const float* __restrict__ ew, const int* __restrict__ rowptr,
                      const int* __restrict__ bsum,
                      int* __restrict__ cnt, int* __restrict__ rank,
                      int2* __restrict__ rec, int ne)
{
    constexpr int LDA = BK + 8;   // pad: 72 shorts = 144 B = 36 banks
    constexpr int LDB = BK + 8;
    __shared__ unsigned short As[BM * LDA];
    __shared__ unsigned short Bs[BN * LDB];

    if ((int)blockIdx.x >= gemm_blocks) {
        // ---- edge task ----
        int e = ((int)blockIdx.x - gemm_blocks) * 256 + threadIdx.x;
        if (e < ne) {
            if constexpr (!FILL) {
                rank[e] = atomicAdd(&cnt[dst[e]], 1);
            } else {
                int d = dst[e];
                int pos = rowptr[d] + bsum[d >> 8] + rank[e];
                rec[pos] = make_int2(src[e], __float_as_int(ew[e]));
            }
        }
        return;
    }

    // ---- GEMM slice ----
    const int tid  = threadIdx.x;
    const int wave = tid >> 6;
    const int lane = tid & 63;
    const int lr   = lane & 15;
    const int quad = lane >> 4;
    const int row0 = row_base + (int)blockIdx.x * BM;

    f32x4 acc[2][TN];
#pragma unroll
    for (int i = 0; i < 2; i++)
#pragma unroll
        for (int j = 0; j < TN; j++) acc[i][j] = (f32x4)0.f;

    for (int k0 = 0; k0 < K; k0 += BK) {
        // --- stage A tile (BM x BK) fp32 -> bf16 ---
#pragma unroll
        for (int l = tid; l < BM * (BK / 4); l += 256) {
            int m  = l / (BK / 4);
            int kq = l % (BK / 4);
            int rg = row0 + m; if (rg >= M) rg = M - 1;
            float4 v = *(const float4*)(A + (long long)rg * K + k0 + kq * 4);
            ushort4 b = make_ushort4(f2bf(v.x), f2bf(v.y), f2bf(v.z), f2bf(v.w));
            *(ushort4*)(&As[m * LDA + kq * 4]) = b;
        }
        // --- stage B tile (BN x BK) from Bt[N,K] (already bf16) ---
#pragma unroll
        for (int l = tid; l < BN * (BK / 8); l += 256) {
            int n  = l / (BK / 8);
            int ko = l % (BK / 8);
            uint4 v = *(const uint4*)(Bt + (long long)n * K + k0 + ko * 8);
            *(uint4*)(&Bs[n * LDB + ko * 8]) = v;
        }
        __syncthreads();

#pragma unroll
        for (int kk = 0; kk < BK; kk += 32) {
            bf16x8 a[2], b[TN];
#pragma unroll
            for (int tm = 0; tm < 2; tm++)
                a[tm] = *(const bf16x8*)(&As[(wave * 32 + tm * 16 + lr) * LDA + kk + quad * 8]);
#pragma unroll
            for (int tn = 0; tn < TN; tn++)
                b[tn] = *(const bf16x8*)(&Bs[(tn * 16 + lr) * LDB + kk + quad * 8]);
#pragma unroll
            for (int tm = 0; tm < 2; tm++)
#pragma unroll
                for (int tn = 0; tn < TN; tn++)
                    acc[tm][tn] = __builtin_amdgcn_mfma_f32_16x16x32_bf16(
                        a[tm], b[tn], acc[tm][tn], 0, 0, 0);
        }
        __syncthreads();
    }

    // --- epilogue: C/D layout col=lane&15, row=quad*4+reg; store fp16 ---
#pragma unroll
    for (int tm = 0; tm < 2; tm++) {
#pragma unroll
        for (int r = 0; r < 4; r++) {
            int row = row0 + wave * 32 + tm * 16 + quad * 4 + r;
            if (row < M) {
#pragma unroll
                for (int tn = 0; tn < TN; tn++)
                    C[(long long)row * N + tn * 16 + lr] = f2h(acc[tm][tn][r]);
            }
        }
    }
}

// ---------------------------------------------------------------------------
// CSR scan: scan1 covers i <= n (cnt[NN]=0), so rowptr[i]+bsum[i>>8] is the
// final exclusive prefix for ALL i in [0, NN] -- no scan3 pass needed.
// ---------------------------------------------------------------------------
__global__ __launch_bounds__(256)
void scan1_kernel(const int* __restrict__ cnt, int* __restrict__ rowptr,
                  int* __restrict__ bsum, int n)
{
    __shared__ int s[256];
    int t = threadIdx.x;
    int i = blockIdx.x * 256 + t;
    int v = (i <= n) ? cnt[i] : 0;
    s[t] = v;
    __syncthreads();
#pragma unroll
    for (int off = 1; off < 256; off <<= 1) {
        int x = (t >= off) ? s[t - off] : 0;
        __syncthreads();
        s[t] += x;
        __syncthreads();
    }
    if (i <= n) rowptr[i] = s[t] - v;
    if (t == 255) bsum[blockIdx.x] = s[255];
}

__global__ __launch_bounds__(512)
void scan2_kernel(int* __restrict__ bsum, int nb)
{
    __shared__ int s[512];
    int t = threadIdx.x;
    int v = (t < nb) ? bsum[t] : 0;
    s[t] = v;
    __syncthreads();
#pragma unroll
    for (int off = 1; off < 512; off <<= 1) {
        int x = (t >= off) ? s[t - off] : 0;
        __syncthreads();
        s[t] += x;
        __syncthreads();
    }
    if (t < nb) bsum[t] = s[t] - v;
}

// ---------------------------------------------------------------------------
// Fused aggregation layer 1 + gemm2: 16 nodes/block, 4 waves.
// Each wave: 2 iterations x 2 nodes (lanes 0-31 node A, 32-63 node B);
// each lane holds 4 feats (uint2 = 4 fp16) -> full 256-B row per half-wave.
// Then per-wave h@W2 (16-col slab) via 4 MFMAs from the LDS bf16 h tile.
// ---------------------------------------------------------------------------
__global__ __launch_bounds__(256)
void agg1_fused_kernel(const unsigned int* __restrict__ sup, const int2* __restrict__ rec,
                       const int* __restrict__ rowptr, const int* __restrict__ bsum,
                       const float* __restrict__ b1,
                       const unsigned short* __restrict__ W2t,
                       float* __restrict__ h, unsigned short* __restrict__ sup2, int n)
{
    constexpr int LDH = F1 + 8;                 // 136 shorts = 272 B
    __shared__ unsigned short hsb[16 * LDH];    // 4.25 KB

    const int tid  = threadIdx.x;
    const int w    = tid >> 6;
    const int lane = tid & 63;
    const int half = lane >> 5;
    const int sl   = lane & 31;
    const int base = blockIdx.x * 16;

    float4 bb = *(const float4*)(b1 + sl * 4);

#pragma unroll
    for (int it = 0; it < 2; it++) {
        int row  = w * 4 + it * 2 + half;
        int node = base + row;
        float4 acc = make_float4(0.f, 0.f, 0.f, 0.f);
        if (node < n) {
            int j   = rowptr[node]     + bsum[node >> 8];
            int end = rowptr[node + 1] + bsum[(node + 1) >> 8];
            for (; j + 8 <= end; j += 8) {
                int2 r[8];
#pragma unroll
                for (int u = 0; u < 8; u++) r[u] = rec[j + u];
                uint2 uu[8];
#pragma unroll
                for (int u = 0; u < 8; u++)
                    uu[u] = *(const uint2*)(&sup[(long long)r[u].x * 64 + sl * 2]);
#pragma unroll
                for (int u = 0; u < 8; u++) {
                    float2 fa = h2f2(uu[u].x);
                    float2 fb = h2f2(uu[u].y);
                    float  ww = __int_as_float(r[u].y);
                    acc.x = fmaf(fa.x, ww, acc.x);
                    acc.y = fmaf(fa.y, ww, acc.y);
                    acc.z = fmaf(fb.x, ww, acc.z);
                    acc.w = fmaf(fb.y, ww, acc.w);
                }
            }
            for (; j < end; j++) {
                int2 r0 = rec[j];
                uint2 u0 = *(const uint2*)(&sup[(long long)r0.x * 64 + sl * 2]);
                float2 fa = h2f2(u0.x);
                float2 fb = h2f2(u0.y);
                float  ww = __int_as_float(r0.y);
                acc.x = fmaf(fa.x, ww, acc.x);
                acc.y = fmaf(fa.y, ww, acc.y);
                acc.z = fmaf(fb.x, ww, acc.z);
                acc.w = fmaf(fb.y, ww, acc.w);
            }
            acc.x += bb.x;  acc.y += bb.y;  acc.z += bb.z;  acc.w += bb.w;
            acc.x = acc.x > 0.f ? acc.x : 0.01f * acc.x;
            acc.y = acc.y > 0.f ? acc.y : 0.01f * acc.y;
            acc.z = acc.z > 0.f ? acc.z : 0.01f * acc.z;
            acc.w = acc.w > 0.f ? acc.w : 0.01f * acc.w;
            *(float4*)(h + (long long)node * 128 + sl * 4) = acc;
        }
        ushort4 hv = (node < n)
            ? make_ushort4(f2bf(acc.x), f2bf(acc.y), f2bf(acc.z), f2bf(acc.w))
            : make_ushort4(0, 0, 0, 0);
        *(ushort4*)(&hsb[row * LDH + sl * 4]) = hv;
    }
    __syncthreads();

    // --- h @ W2 for this block's 16 nodes; wave w -> cols [w*16, w*16+16) ---
    const int lr   = lane & 15;
    const int quad = lane >> 4;
    f32x4 acc2 = (f32x4)0.f;
#pragma unroll
    for (int kk = 0; kk < F1; kk += 32) {
        bf16x8 a = *(const bf16x8*)(&hsb[lr * LDH + kk + quad * 8]);
        bf16x8 b = *(const bf16x8*)(W2t + (w * 16 + lr) * F1 + kk + quad * 8);
        acc2 = __builtin_amdgcn_mfma_f32_16x16x32_bf16(a, b, acc2, 0, 0, 0);
    }
#pragma unroll
    for (int r = 0; r < 4; r++) {
        int node = base + quad * 4 + r;
        if (node < n)
            sup2[(long long)node * 64 + w * 16 + lr] = f2h(acc2[r]);
    }
}

// ---------------------------------------------------------------------------
// Fused aggregation layer 2 + softmax: 2 nodes/wave (32-lane halves),
// each lane holds 2 feats (uint = 2 fp16) -> full 128-B row per half-wave.
// Softmax reduced within each 32-lane half (offsets 16..1).
// ---------------------------------------------------------------------------
__global__ __launch_bounds__(256)
void agg2_kernel(const unsigned short* __restrict__ sup, const int2* __restrict__ rec,
                 const int* __restrict__ rowptr, const int* __restrict__ bsum,
                 const float* __restrict__ b2, float* __restrict__ out, int n)
{
    const int lane = threadIdx.x & 63;
    const int half = lane >> 5;
    const int sl   = lane & 31;
    const int node = blockIdx.x * 8 + (threadIdx.x >> 6) * 2 + half;
    if (node >= n) return;

    int j   = rowptr[node]     + bsum[node >> 8];
    int end = rowptr[node + 1] + bsum[(node + 1) >> 8];
    float2 acc = make_float2(0.f, 0.f);

    for (; j + 8 <= end; j += 8) {
        int2 r[8];
#pragma unroll
        for (int u = 0; u < 8; u++) r[u] = rec[j + u];
        unsigned int uu[8];
#pragma unroll
        for (int u = 0; u < 8; u++)
            uu[u] = *(const unsigned int*)(&sup[(long long)r[u].x * 64 + sl * 2]);
#pragma unroll
        for (int u = 0; u < 8; u++) {
            float2 f = h2f2(uu[u]);
            float  ww = __int_as_float(r[u].y);
            acc.x = fmaf(f.x, ww, acc.x);
            acc.y = fmaf(f.y, ww, acc.y);
        }
    }
    for (; j < end; j++) {
        int2 r0 = rec[j];
        unsigned int u0 = *(const unsigned int*)(&sup[(long long)r0.x * 64 + sl * 2]);
        float2 f = h2f2(u0);
        float  ww = __int_as_float(r0.y);
        acc.x = fmaf(f.x, ww, acc.x);
        acc.y = fmaf(f.y, ww, acc.y);
    }

    float2 bv = *(const float2*)(b2 + sl * 2);
    float2 v  = make_float2(acc.x + bv.x, acc.y + bv.y);
    float m = fmaxf(v.x, v.y);
#pragma unroll
    for (int off = 16; off; off >>= 1) m = fmaxf(m, __shfl_xor(m, off, 64));
    float2 e = make_float2(__expf(v.x - m), __expf(v.y - m));
    float s = e.x + e.y;
#pragma unroll
    for (int off = 16; off; off >>= 1) s += __shfl_xor(s, off, 64);
    float inv = 1.f / s;
    *(float2*)(out + (long long)node * 64 + sl * 2) = make_float2(e.x * inv, e.y * inv);
}

// ---------------------------------------------------------------------------
extern "C" void kernel_launch(void* const* d_in, const int* in_sizes, int n_in,
                              void* d_out, int out_size, void* d_ws, size_t ws_size,
                              hipStream_t stream)
{
    const float* y   = (const float*)d_in[0];   // [NN, F0]
    const int*   src = (const int*)  d_in[1];   // [NE]
    const int*   dst = (const int*)  d_in[2];   // [NE]
    const float* ew  = (const float*)d_in[3];   // [NE]
    const float* W1  = (const float*)d_in[4];   // [F0, F1]
    const float* b1  = (const float*)d_in[5];   // [F1]
    const float* W2  = (const float*)d_in[6];   // [F1, F2]
    const float* b2  = (const float*)d_in[7];   // [F2]

    float* out     = (float*)d_out;
    float* softout = out;                              // [NN, F2]
    float* h       = out + (size_t)NN * F2;            // [NN, F1] embedding

    // ---- workspace layout (256B-aligned chunks; total ~58.6 MB) ----
    char* ws = (char*)d_ws;
    size_t o = 0;
    auto alloc = [&](size_t bytes) -> void* {
        void* p = ws + o;
        o = (o + bytes + 255) & ~(size_t)255;
        return p;
    };
    unsigned short* sup  = (unsigned short*)alloc((size_t)NN * F1 * 2); // fp16 layer-1 support
    unsigned short* sup2 = (unsigned short*)alloc((size_t)NN * F2 * 2); // fp16 layer-2 support
    int2*           rec  = (int2*)          alloc((size_t)NE * 8);
    int*            rank = (int*)           alloc((size_t)NE * 4);
    int*            rowptr = (int*)         alloc((size_t)(NN + 2) * 4);
    int*            cnt  = (int*)           alloc((size_t)(NN + 256) * 4);
    int*            bsum = (int*)           alloc(512 * 4);
    unsigned short* W1t  = (unsigned short*)alloc((size_t)F0 * F1 * 2);
    unsigned short* W2t  = (unsigned short*)alloc((size_t)F1 * F2 * 2);

    const int NB = (NN + 255) / 256;          // 391 scan blocks
    const int GB = (NN + 127) / 128;          // 782 gemm1 blocks total
    const int GA = 312;                       // first-half blocks (rebalanced)
    const int EB = (NE + 255) / 256;          // 6250 edge blocks

    // ---- weights transpose + cnt zero (one launch, 391 blocks) ----
    wt_kernel<<<NB, 256, 0, stream>>>(W1, W2, W1t, W2t, cnt, NB * 256);

    // ---- [gemm1 first slice || histogram+rank] ----
    gemm_edge_kernel<128, 128, 64, 8, false><<<GA + EB, 256, 0, stream>>>(
        y, W1t, sup, NN, F0, F1, /*row_base=*/0, /*gemm_blocks=*/GA,
        src, dst, ew, rowptr, bsum, cnt, rank, rec, NE);

    // ---- CSR scan (2 kernels; scan3 folded into consumers) ----
    scan1_kernel<<<NB, 256, 0, stream>>>(cnt, rowptr, bsum, NN);
    scan2_kernel<<<1, 512, 0, stream>>>(bsum, NB);

    // ---- [gemm1 second slice || CSR fill] ----
    gemm_edge_kernel<128, 128, 64, 8, true><<<(GB - GA) + EB, 256, 0, stream>>>(
        y, W1t, sup, NN, F0, F1, /*row_base=*/GA * 128, /*gemm_blocks=*/GB - GA,
        src, dst, ew, rowptr, bsum, cnt, rank, rec, NE);

    // ---- fused: gather-agg + bias + leaky-relu -> h; h @ W2 -> sup2 ----
    agg1_fused_kernel<<<(NN + 15) / 16, 256, 0, stream>>>(
        (const unsigned int*)sup, rec, rowptr, bsum, b1, W2t, h, sup2, NN);

    // ---- layer 2 aggregation + softmax ----
    agg2_kernel<<<(NN + 7) / 8, 256, 0, stream>>>(
        sup2, rec, rowptr, bsum, b2, softout, NN);
}